// Round 14
// baseline (3872.119 us; speedup 1.0000x reference)
//
#include <hip/hip_runtime.h>

// QINCo round 14: R10 loop shape at 2x occupancy.
// k_step: 512 threads = 8 waves (ht = w>>1 in 0..3, mb = w&1).
//  Per hf: GEMM1 -> 8 wave-tiles (4 h-tiles x 2 m-tiles), acc1[1];
//          GEMM2 -> 8 wave-tiles (4 d-tiles x 2 m-tiles), acc2[1] across hf.
//  A-fragments batch-preloaded per hf (R10-proven: one vmcnt drain, no
//  per-kc loads on the critical path). LDS/barriers/epilogues = R10.
//  64KB LDS -> 2 blocks/CU -> 16 waves/CU (50% occ, was 22%).
// Shapes: D=128, M=8, K=256, L=2, H=256, BS=1024.
// Out layout (floats): xhat[1024*128] | codes[1024*8] | side[8][1024*128]

typedef _Float16 f16;
typedef f16 half4_t __attribute__((ext_vector_type(4)));
typedef f16 half8_t __attribute__((ext_vector_type(8)));
typedef float f32x16 __attribute__((ext_vector_type(16)));

#define OUT_CODES 131072
#define OUT_SIDE  139264

// ws float offsets
#define WS_XHAT  0          // [1024][128]
#define WS_RB    131072     // [1024][128]  r = x - xhat
#define WS_Y     262144     // [1024][128]  y = xhat @ Wx^T
#define WS_ZC    393216     // [256][128]   zc = cb + cb@Wz^T + bc
#define WS_BESTD 425984     // [1024][4]
#define WS_BESTI 430080     // [1024][4] (int)
#define WS_BESTZ 434176     // [1024][4][128]
#define WS_WSPLIT 960000    // f16 region: W1H|W1L|W2H|W2L, NW1 halfs each
#define NW1 458752          // 7*2*256*128

#define HLO 8192            // hi->lo LDS offset (halfs), compile-time

__device__ __forceinline__ f32x16 mfma_f16(half8_t a, half8_t b, f32x16 c) {
  return __builtin_amdgcn_mfma_f32_32x32x16_f16(a, b, c, 0, 0, 0);
}

// ---------------- weight pre-split: fp32 -> scaled (x256) fp16 hi/lo ----------------
__global__ __launch_bounds__(256) void k_wsplit(const float* __restrict__ W1,
    const float* __restrict__ W2, f16* __restrict__ wsh)
{
  int i = (blockIdx.x * 256 + threadIdx.x) * 4;      // [0, 2*NW1)
  const float* src;
  f16* hi;
  if (i < NW1) { src = W1 + i; hi = wsh + i; }
  else         { src = W2 + (i - NW1); hi = wsh + 2 * NW1 + (i - NW1); }
  f16* lo = hi + NW1;
  float4 v = *(const float4*)src;
  half4_t h, l;
  float s;
  s = v.x * 256.f; h[0] = (f16)s; l[0] = (f16)(s - (float)h[0]);
  s = v.y * 256.f; h[1] = (f16)s; l[1] = (f16)(s - (float)h[1]);
  s = v.z * 256.f; h[2] = (f16)s; l[2] = (f16)(s - (float)h[2]);
  s = v.w * 256.f; h[3] = (f16)s; l[3] = (f16)(s - (float)h[3]);
  *(half4_t*)hi = h;
  *(half4_t*)lo = l;
}

// ---------------- step 0: nearest codebook0 row ----------------
__global__ __launch_bounds__(256) void k_step0(const float* __restrict__ x,
    const float* __restrict__ cb0, float* __restrict__ ws, float* __restrict__ out)
{
  __shared__ float xs[128];
  __shared__ float redv[4];
  __shared__ int   redi[4];
  __shared__ int   kwin;
  int tx = threadIdx.x, b = blockIdx.x;
  if (tx < 128) xs[tx] = x[b * 128 + tx];
  __syncthreads();
  const float* c = cb0 + tx * 128;   // k = tx
  float s = 0.f;
  for (int d = 0; d < 128; d += 4) {
    float4 cv = *(const float4*)(c + d);
    float4 xv = *(const float4*)(xs + d);
    float a0 = xv.x - cv.x, a1 = xv.y - cv.y, a2 = xv.z - cv.z, a3 = xv.w - cv.w;
    s += a0 * a0 + a1 * a1 + a2 * a2 + a3 * a3;
  }
  float v = s; int idx = tx;
  for (int off = 32; off; off >>= 1) {
    float v2 = __shfl_xor(v, off);
    int   i2 = __shfl_xor(idx, off);
    if (v2 < v || (v2 == v && i2 < idx)) { v = v2; idx = i2; }
  }
  if ((tx & 63) == 0) { redv[tx >> 6] = v; redi[tx >> 6] = idx; }
  __syncthreads();
  if (tx == 0) {
    float bv = redv[0]; int bi = redi[0];
    for (int w = 1; w < 4; w++)
      if (redv[w] < bv || (redv[w] == bv && redi[w] < bi)) { bv = redv[w]; bi = redi[w]; }
    kwin = bi;
    out[OUT_CODES + b * 8] = (float)bi;
  }
  __syncthreads();
  int k = kwin;
  if (tx < 128) {
    float xh = cb0[k * 128 + tx];
    ws[WS_XHAT + b * 128 + tx] = xh;
    ws[WS_RB   + b * 128 + tx] = xs[tx] - xh;
    out[OUT_SIDE + b * 128 + tx] = xh;   // side[0]
  }
}

// ---------------- per-step prep: zc and y (fp32) ----------------
__global__ __launch_bounds__(128) void k_prep(const float* __restrict__ cb,
    const float* __restrict__ Wc, const float* __restrict__ bcm, float* __restrict__ ws)
{
  __shared__ float row[128];
  int tx = threadIdx.x, blk = blockIdx.x;
  if (blk < 256) {          // zc[k][i] = cb[k][i] + sum_d cb[k][d]*Wc[i][d] + bc[i]
    row[tx] = cb[blk * 128 + tx];
    __syncthreads();
    const float* wrow = Wc + tx * 256;
    float s = 0.f;
    for (int d = 0; d < 128; d += 4) {
      float4 wv = *(const float4*)(wrow + d);
      float4 zv = *(const float4*)(row + d);
      s += wv.x * zv.x + wv.y * zv.y + wv.z * zv.z + wv.w * zv.w;
    }
    ws[WS_ZC + blk * 128 + tx] = row[tx] + s + bcm[tx];
  } else {                  // y[b][i] = sum_d xhat[b][d]*Wc[i][128+d]
    int b = blk - 256;
    row[tx] = ws[WS_XHAT + b * 128 + tx];
    __syncthreads();
    const float* wrow = Wc + tx * 256 + 128;
    float s = 0.f;
    for (int d = 0; d < 128; d += 4) {
      float4 wv = *(const float4*)(wrow + d);
      float4 zv = *(const float4*)(row + d);
      s += wv.x * zv.x + wv.y * zv.y + wv.z * zv.z + wv.w * zv.w;
    }
    ws[WS_Y + b * 128 + tx] = s;
  }
}

// ---------------- main step kernel ----------------
// 512 threads = 8 waves; wave w: ht = w>>1 (0..3), mb = w&1.
// lane: col = lane&31, koct = lane>>5.
// LDS rows 128 halfs; logical d of row m at phys (d + 8*(m&15)) & 127.
// GEMM1 per hf: wave (ht,mb) -> H^T rows h = hf*128 + 32ht + Crow,
//   m-tile mb (B rows 32mb+col). acc1[1].
// GEMM2 per hf: wave (ht,mb) -> d rows 32ht + Crow, m-tile mb, K = hf's 128.
//   acc2[1] accumulated across hf.
// C/D layout: col = m-in-tile; Crow = (reg&3)+8*(reg>>2)+4*koct.
__global__ __launch_bounds__(512, 2) void k_step(const f16* __restrict__ wsh,
    float* __restrict__ ws, int sm)
{
  __shared__ __align__(16) f16 lds[32768];     // 64 KB exactly
  f16* Zh = lds;            // [64][128]
  f16* Hh = lds + 2 * HLO;  // [64][128]; lo halves at +HLO from each
  int tx = threadIdx.x;
  int lane = tx & 63, w = tx >> 6;
  int col = lane & 31, koct = lane >> 5;
  int ht = w >> 1, mb = w & 1;
  int b = blockIdx.x >> 2, t = blockIdx.x & 3, k0 = t << 6;

  // ---- init Z = zc[k0+m] + y[b], split x256 into Zh/Zl (rotated store) ----
  {
    const float* zc = ws + WS_ZC + k0 * 128;
    const float* y  = ws + WS_Y + b * 128;
    for (int idx = tx; idx < 1024; idx += 512) {
      int m = idx & 63, d0 = (idx >> 6) << 3;
      float4 a  = *(const float4*)(zc + m * 128 + d0);
      float4 bb = *(const float4*)(zc + m * 128 + d0 + 4);
      float4 ya = *(const float4*)(y + d0);
      float4 yb = *(const float4*)(y + d0 + 4);
      float sv[8] = {a.x + ya.x, a.y + ya.y, a.z + ya.z, a.w + ya.w,
                     bb.x + yb.x, bb.y + yb.y, bb.z + yb.z, bb.w + yb.w};
      half8_t h8, l8;
#pragma unroll
      for (int j = 0; j < 8; j++) {
        float v = sv[j] * 256.f;
        f16 h = (f16)v; h8[j] = h; l8[j] = (f16)(v - (float)h);
      }
      int c0 = (d0 + ((m & 15) << 3)) & 127;
      *(half8_t*)(Zh + (m << 7) + c0) = h8;
      *(half8_t*)(Zh + HLO + (m << 7) + c0) = l8;
    }
  }
  __syncthreads();

  const int mrow = (mb << 5) + col;        // B row for both GEMMs
  const int rot0 = (col & 15) << 3;        // rotation for row mrow
  const f16* Zr = Zh + (mrow << 7);
  const f16* Hr = Hh + (mrow << 7);

  for (int l = 0; l < 2; l++) {
    const f16* w1h = wsh + (size_t)((sm * 2 + l) * 256) * 128;
    const f16* w2h = wsh + 2 * NW1 + (size_t)((sm * 2 + l) * 128) * 256;
    f32x16 acc2;
#pragma unroll
    for (int i = 0; i < 16; i++) acc2[i] = 0.f;

#pragma unroll
    for (int hf = 0; hf < 2; hf++) {
      // ---- batch-preload A fragments (GEMM1 then GEMM2): one vmcnt drain ----
      const f16* a1p = w1h + (size_t)((hf << 7) + (ht << 5) + col) * 128 + (koct << 3);
      const f16* a2p = w2h + (size_t)((ht << 5) + col) * 256 + (hf << 7) + (koct << 3);
      half8_t a1hv[8], a1lv[8], a2hv[8], a2lv[8];
#pragma unroll
      for (int kc = 0; kc < 8; kc++) {
        a1hv[kc] = *(const half8_t*)(a1p + (kc << 4));
        a1lv[kc] = *(const half8_t*)(a1p + NW1 + (kc << 4));
      }
#pragma unroll
      for (int kc = 0; kc < 8; kc++) {
        a2hv[kc] = *(const half8_t*)(a2p + (kc << 4));
        a2lv[kc] = *(const half8_t*)(a2p + NW1 + (kc << 4));
      }

      // ---- GEMM1: single tile, pure LDS + MFMA ----
      f32x16 acc1;
#pragma unroll
      for (int i = 0; i < 16; i++) acc1[i] = 0.f;
#pragma unroll
      for (int kc = 0; kc < 8; kc++) {
        int poff = (((kc << 4) + (koct << 3)) + rot0) & 127;
        half8_t bh = *(const half8_t*)(Zr + poff);
        half8_t bl = *(const half8_t*)(Zr + HLO + poff);
        acc1 = mfma_f16(a1hv[kc], bh, acc1);
        acc1 = mfma_f16(a1lv[kc], bh, acc1);
        acc1 = mfma_f16(a1hv[kc], bl, acc1);
      }
      // epilogue1: relu, rescale (x 2^-8), split, store H[mrow][32ht + Crow]
#pragma unroll
      for (int qd = 0; qd < 4; qd++) {
        half4_t hv, lv;
#pragma unroll
        for (int j = 0; j < 4; j++) {
          float tv = fmaxf(acc1[(qd << 2) + j], 0.f) * 0.00390625f;
          f16 h = (f16)tv; hv[j] = h; lv[j] = (f16)(tv - (float)h);
        }
        int c = (((ht << 5) + (qd << 3) + (koct << 2)) + rot0) & 127;
        *(half4_t*)(Hh + (mrow << 7) + c) = hv;
        *(half4_t*)(Hh + HLO + (mrow << 7) + c) = lv;
      }
      __syncthreads();
      // ---- GEMM2 partial: single tile, pure LDS + MFMA ----
#pragma unroll
      for (int kc = 0; kc < 8; kc++) {
        int poff = (((kc << 4) + (koct << 3)) + rot0) & 127;
        half8_t bh = *(const half8_t*)(Hr + poff);
        half8_t bl = *(const half8_t*)(Hr + HLO + poff);
        acc2 = mfma_f16(a2hv[kc], bh, acc2);
        acc2 = mfma_f16(a2lv[kc], bh, acc2);
        acc2 = mfma_f16(a2hv[kc], bl, acc2);
      }
      __syncthreads();
    }
    // ---- epilogue2: Z[mrow][32ht + Crow] += acc2 * 2^-8 (scaled units) ----
    {
      f16* zhr = Zh + (mrow << 7);
#pragma unroll
      for (int qd = 0; qd < 4; qd++) {
        int c = (((ht << 5) + (qd << 3) + (koct << 2)) + rot0) & 127;
        half4_t zh = *(half4_t*)(zhr + c);
        half4_t zl = *(half4_t*)(zhr + HLO + c);
#pragma unroll
        for (int j = 0; j < 4; j++) {
          float zs = (float)zh[j] + (float)zl[j];
          zs += acc2[(qd << 2) + j] * 0.00390625f;
          f16 h = (f16)zs; zh[j] = h; zl[j] = (f16)(zs - (float)h);
        }
        *(half4_t*)(zhr + c) = zh;
        *(half4_t*)(zhr + HLO + c) = zl;
      }
    }
    __syncthreads();
  }

  // ---- dist = ||rb - z||^2 over 64 rows (8 threads/row, 16 d each) ----
  float* pd = (float*)Hh;
  int* rwin = (int*)Hh + 64;
  {
    int row = tx >> 3, seg = tx & 7;
    int rotr = (row & 15) << 3;
    const f16* zhr = Zh + (row << 7);
    const float* rb = ws + WS_RB + b * 128 + (seg << 4);
    float s = 0.f;
#pragma unroll
    for (int o = 0; o < 2; o++) {
      int c = (((seg << 4) + (o << 3)) + rotr) & 127;
      half8_t zh = *(const half8_t*)(zhr + c);
      half8_t zl = *(const half8_t*)(zhr + HLO + c);
      float4 r0 = *(const float4*)(rb + (o << 3));
      float4 r1 = *(const float4*)(rb + (o << 3) + 4);
      float rr[8] = {r0.x, r0.y, r0.z, r0.w, r1.x, r1.y, r1.z, r1.w};
#pragma unroll
      for (int j = 0; j < 8; j++) {
        float z = ((float)zh[j] + (float)zl[j]) * 0.00390625f;
        float dlt = rr[j] - z;
        s += dlt * dlt;
      }
    }
    s += __shfl_xor(s, 1);   // all 8 lanes of a row end bit-identical
    s += __shfl_xor(s, 2);
    s += __shfl_xor(s, 4);
    if (seg == 0) pd[row] = s;
  }
  __syncthreads();
  if (tx < 64) {
    float v = pd[tx]; int idx = tx;
#pragma unroll
    for (int off = 32; off; off >>= 1) {
      float v2 = __shfl_xor(v, off);
      int   i2 = __shfl_xor(idx, off);
      if (v2 < v || (v2 == v && i2 < idx)) { v = v2; idx = i2; }
    }
    if (tx == 0) {
      ws[WS_BESTD + (b << 2) + t] = v;
      ((int*)ws)[WS_BESTI + (b << 2) + t] = k0 + idx;
      rwin[0] = idx;
    }
  }
  __syncthreads();
  if (tx < 32) {
    int rw = rwin[0];
    int c = ((tx << 2) + ((rw & 15) << 3)) & 127;
    half4_t zh = *(const half4_t*)(Zh + (rw << 7) + c);
    half4_t zl = *(const half4_t*)(Zh + HLO + (rw << 7) + c);
    float4 z;
    z.x = ((float)zh[0] + (float)zl[0]) * 0.00390625f;
    z.y = ((float)zh[1] + (float)zl[1]) * 0.00390625f;
    z.z = ((float)zh[2] + (float)zl[2]) * 0.00390625f;
    z.w = ((float)zh[3] + (float)zl[3]) * 0.00390625f;
    *(float4*)(ws + WS_BESTZ + (((b << 2) + t) << 7) + (tx << 2)) = z;
  }
}

// ---------------- per-step update: pick tile winner, advance xhat ----------------
__global__ __launch_bounds__(128) void k_update(const float* __restrict__ x,
    float* __restrict__ ws, float* __restrict__ out, int m, int last)
{
  __shared__ int tsel;
  int tx = threadIdx.x, b = blockIdx.x;
  if (tx == 0) {
    float bv = ws[WS_BESTD + (b << 2)]; int bt = 0;
    for (int q = 1; q < 4; q++) {
      float v = ws[WS_BESTD + (b << 2) + q];
      if (v < bv) { bv = v; bt = q; }     // strict <: ties -> lowest k (tile order)
    }
    tsel = bt;
    int k = ((const int*)ws)[WS_BESTI + (b << 2) + bt];
    out[OUT_CODES + b * 8 + (m + 1)] = (float)k;
  }
  __syncthreads();
  int bt = tsel;
  float z  = ws[WS_BESTZ + (((b << 2) + bt) << 7) + tx];
  float xh = ws[WS_XHAT + b * 128 + tx] + z;
  ws[WS_XHAT + b * 128 + tx] = xh;
  ws[WS_RB   + b * 128 + tx] = x[b * 128 + tx] - xh;
  out[OUT_SIDE + (m + 1) * 131072 + b * 128 + tx] = xh;
  if (last) out[b * 128 + tx] = xh;       // final xhat == side[7]
}

extern "C" void kernel_launch(void* const* d_in, const int* in_sizes, int n_in,
                              void* d_out, int out_size, void* d_ws, size_t ws_size,
                              hipStream_t stream)
{
  const float* x   = (const float*)d_in[0];
  const float* cb0 = (const float*)d_in[1];
  const float* cbs = (const float*)d_in[2];
  const float* Wc  = (const float*)d_in[3];
  const float* bc  = (const float*)d_in[4];
  const float* W1  = (const float*)d_in[5];
  const float* W2  = (const float*)d_in[6];
  float* out = (float*)d_out;
  float* ws  = (float*)d_ws;
  f16* wsh = (f16*)(ws + WS_WSPLIT);

  k_wsplit<<<896, 256, 0, stream>>>(W1, W2, wsh);
  k_step0<<<1024, 256, 0, stream>>>(x, cb0, ws, out);
  for (int m = 0; m < 7; m++) {
    k_prep<<<1280, 128, 0, stream>>>(cbs + m * 256 * 128, Wc + m * 128 * 256,
                                     bc + m * 128, ws);
    k_step<<<4096, 512, 0, stream>>>(wsh, ws, m);
    k_update<<<1024, 128, 0, stream>>>(x, ws, out, m, (m == 6) ? 1 : 0);
  }
}

// Round 15
// 3667.385 us; speedup vs baseline: 1.0558x; 1.0558x over previous
//
#include <hip/hip_runtime.h>

// QINCo round 15: R13's B-sharing + R10's batch A-preload (the one combo
// satisfying all four measured constraints: batch preload, >=2 chains,
// live VGPR <= ~150, 2 LDS reads per kc).
//  Wave (mb,hg): m-tile mb (B rows 32mb+col), A-tiles {2hg,2hg+1}.
//  Per kc: 2 LDS b128 (shared bh/bl) + 6 MFMA (2 A-tile chains).
//  A hi/lo for both GEMMs preloaded upfront per hf (R10-proven schedule).
//  LDS: Zh|Zl|Hh|Hl [64][128] halfs (64KB), rotation-by-8 layout.
// Shapes: D=128, M=8, K=256, L=2, H=256, BS=1024.
// Out layout (floats): xhat[1024*128] | codes[1024*8] | side[8][1024*128]

typedef _Float16 f16;
typedef f16 half4_t __attribute__((ext_vector_type(4)));
typedef f16 half8_t __attribute__((ext_vector_type(8)));
typedef float f32x16 __attribute__((ext_vector_type(16)));

#define OUT_CODES 131072
#define OUT_SIDE  139264

// ws float offsets
#define WS_XHAT  0          // [1024][128]
#define WS_RB    131072     // [1024][128]  r = x - xhat
#define WS_Y     262144     // [1024][128]  y = xhat @ Wx^T
#define WS_ZC    393216     // [256][128]   zc = cb + cb@Wz^T + bc
#define WS_BESTD 425984     // [1024][4]
#define WS_BESTI 430080     // [1024][4] (int)
#define WS_BESTZ 434176     // [1024][4][128]
#define WS_WSPLIT 960000    // f16 region: W1H|W1L|W2H|W2L, NW1 halfs each
#define NW1 458752          // 7*2*256*128

#define HLO 8192            // hi->lo LDS offset (halfs), compile-time

__device__ __forceinline__ f32x16 mfma_f16(half8_t a, half8_t b, f32x16 c) {
  return __builtin_amdgcn_mfma_f32_32x32x16_f16(a, b, c, 0, 0, 0);
}

// ---------------- weight pre-split: fp32 -> scaled (x256) fp16 hi/lo ----------------
__global__ __launch_bounds__(256) void k_wsplit(const float* __restrict__ W1,
    const float* __restrict__ W2, f16* __restrict__ wsh)
{
  int i = (blockIdx.x * 256 + threadIdx.x) * 4;      // [0, 2*NW1)
  const float* src;
  f16* hi;
  if (i < NW1) { src = W1 + i; hi = wsh + i; }
  else         { src = W2 + (i - NW1); hi = wsh + 2 * NW1 + (i - NW1); }
  f16* lo = hi + NW1;
  float4 v = *(const float4*)src;
  half4_t h, l;
  float s;
  s = v.x * 256.f; h[0] = (f16)s; l[0] = (f16)(s - (float)h[0]);
  s = v.y * 256.f; h[1] = (f16)s; l[1] = (f16)(s - (float)h[1]);
  s = v.z * 256.f; h[2] = (f16)s; l[2] = (f16)(s - (float)h[2]);
  s = v.w * 256.f; h[3] = (f16)s; l[3] = (f16)(s - (float)h[3]);
  *(half4_t*)hi = h;
  *(half4_t*)lo = l;
}

// ---------------- step 0: nearest codebook0 row ----------------
__global__ __launch_bounds__(256) void k_step0(const float* __restrict__ x,
    const float* __restrict__ cb0, float* __restrict__ ws, float* __restrict__ out)
{
  __shared__ float xs[128];
  __shared__ float redv[4];
  __shared__ int   redi[4];
  __shared__ int   kwin;
  int tx = threadIdx.x, b = blockIdx.x;
  if (tx < 128) xs[tx] = x[b * 128 + tx];
  __syncthreads();
  const float* c = cb0 + tx * 128;   // k = tx
  float s = 0.f;
  for (int d = 0; d < 128; d += 4) {
    float4 cv = *(const float4*)(c + d);
    float4 xv = *(const float4*)(xs + d);
    float a0 = xv.x - cv.x, a1 = xv.y - cv.y, a2 = xv.z - cv.z, a3 = xv.w - cv.w;
    s += a0 * a0 + a1 * a1 + a2 * a2 + a3 * a3;
  }
  float v = s; int idx = tx;
  for (int off = 32; off; off >>= 1) {
    float v2 = __shfl_xor(v, off);
    int   i2 = __shfl_xor(idx, off);
    if (v2 < v || (v2 == v && i2 < idx)) { v = v2; idx = i2; }
  }
  if ((tx & 63) == 0) { redv[tx >> 6] = v; redi[tx >> 6] = idx; }
  __syncthreads();
  if (tx == 0) {
    float bv = redv[0]; int bi = redi[0];
    for (int w = 1; w < 4; w++)
      if (redv[w] < bv || (redv[w] == bv && redi[w] < bi)) { bv = redv[w]; bi = redi[w]; }
    kwin = bi;
    out[OUT_CODES + b * 8] = (float)bi;
  }
  __syncthreads();
  int k = kwin;
  if (tx < 128) {
    float xh = cb0[k * 128 + tx];
    ws[WS_XHAT + b * 128 + tx] = xh;
    ws[WS_RB   + b * 128 + tx] = xs[tx] - xh;
    out[OUT_SIDE + b * 128 + tx] = xh;   // side[0]
  }
}

// ---------------- per-step prep: zc and y (fp32) ----------------
__global__ __launch_bounds__(128) void k_prep(const float* __restrict__ cb,
    const float* __restrict__ Wc, const float* __restrict__ bcm, float* __restrict__ ws)
{
  __shared__ float row[128];
  int tx = threadIdx.x, blk = blockIdx.x;
  if (blk < 256) {          // zc[k][i] = cb[k][i] + sum_d cb[k][d]*Wc[i][d] + bc[i]
    row[tx] = cb[blk * 128 + tx];
    __syncthreads();
    const float* wrow = Wc + tx * 256;
    float s = 0.f;
    for (int d = 0; d < 128; d += 4) {
      float4 wv = *(const float4*)(wrow + d);
      float4 zv = *(const float4*)(row + d);
      s += wv.x * zv.x + wv.y * zv.y + wv.z * zv.z + wv.w * zv.w;
    }
    ws[WS_ZC + blk * 128 + tx] = row[tx] + s + bcm[tx];
  } else {                  // y[b][i] = sum_d xhat[b][d]*Wc[i][128+d]
    int b = blk - 256;
    row[tx] = ws[WS_XHAT + b * 128 + tx];
    __syncthreads();
    const float* wrow = Wc + tx * 256 + 128;
    float s = 0.f;
    for (int d = 0; d < 128; d += 4) {
      float4 wv = *(const float4*)(wrow + d);
      float4 zv = *(const float4*)(row + d);
      s += wv.x * zv.x + wv.y * zv.y + wv.z * zv.z + wv.w * zv.w;
    }
    ws[WS_Y + b * 128 + tx] = s;
  }
}

// ---------------- main step kernel ----------------
// 256 threads = 4 waves; wave w: mb = w&1, hg = w>>1.
// lane: col = lane&31, koct = lane>>5.
// LDS rows 128 halfs; logical d of row m at phys (d + 8*(m&15)) & 127.
// GEMM1 per hf: A = W1 h-tiles {2hg,2hg+1} of the hf's 128 (preloaded),
//   B = Z rows 32mb+col (LDS, shared by both chains).
// GEMM2 per hf: A = W2 d-tiles {2hg,2hg+1} (preloaded), B = H rows 32mb+col.
//   acc2 accumulated across hf. C/D: col = m-in-tile, row = (reg&3)+8*(reg>>2)+4*koct.
__global__ __launch_bounds__(256, 2) void k_step(const f16* __restrict__ wsh,
    float* __restrict__ ws, int sm)
{
  __shared__ __align__(16) f16 lds[32768];     // 64 KB exactly
  f16* Zh = lds;            // [64][128]
  f16* Hh = lds + 2 * HLO;  // [64][128]; lo halves at +HLO from each
  int tx = threadIdx.x;
  int lane = tx & 63, w = tx >> 6;
  int col = lane & 31, koct = lane >> 5;
  int mb = w & 1, hg = w >> 1;
  int b = blockIdx.x >> 2, t = blockIdx.x & 3, k0 = t << 6;

  // ---- init Z = zc[k0+m] + y[b], split x256 into Zh/Zl (rotated store) ----
  {
    const float* zc = ws + WS_ZC + k0 * 128;
    const float* y  = ws + WS_Y + b * 128;
    for (int idx = tx; idx < 1024; idx += 256) {
      int m = idx & 63, d0 = (idx >> 6) << 3;
      float4 a  = *(const float4*)(zc + m * 128 + d0);
      float4 bb = *(const float4*)(zc + m * 128 + d0 + 4);
      float4 ya = *(const float4*)(y + d0);
      float4 yb = *(const float4*)(y + d0 + 4);
      float sv[8] = {a.x + ya.x, a.y + ya.y, a.z + ya.z, a.w + ya.w,
                     bb.x + yb.x, bb.y + yb.y, bb.z + yb.z, bb.w + yb.w};
      half8_t h8, l8;
#pragma unroll
      for (int j = 0; j < 8; j++) {
        float v = sv[j] * 256.f;
        f16 h = (f16)v; h8[j] = h; l8[j] = (f16)(v - (float)h);
      }
      int c0 = (d0 + ((m & 15) << 3)) & 127;
      *(half8_t*)(Zh + (m << 7) + c0) = h8;
      *(half8_t*)(Zh + HLO + (m << 7) + c0) = l8;
    }
  }
  __syncthreads();

  const int mrow = (mb << 5) + col;        // B row for both GEMMs
  const int rot0 = (col & 15) << 3;        // rotation for row mrow
  const f16* Zr = Zh + (mrow << 7);
  const f16* Hr = Hh + (mrow << 7);

  for (int l = 0; l < 2; l++) {
    const f16* w1h = wsh + (size_t)((sm * 2 + l) * 256) * 128;
    const f16* w2h = wsh + 2 * NW1 + (size_t)((sm * 2 + l) * 128) * 256;
    f32x16 acc2[2];
#pragma unroll
    for (int i = 0; i < 16; i++) { acc2[0][i] = 0.f; acc2[1][i] = 0.f; }

#pragma unroll
    for (int hf = 0; hf < 2; hf++) {
      // A bases: GEMM1 rows h = hf*128 + hg*64 + {0,32} + col
      const f16* a1p = w1h + (size_t)((hf << 7) + (hg << 6) + col) * 128 + (koct << 3);
      // GEMM2 rows d = hg*64 + {0,32} + col, k-base = hf*128
      const f16* a2p = w2h + (size_t)((hg << 6) + col) * 256 + (hf << 7) + (koct << 3);

      // ---- batch-preload A for both GEMMs (R10 schedule: one vmcnt drain,
      //      compiler sinks the a2 batch below GEMM1) ----
      half8_t a1h0[8], a1h1[8], a1l0[8], a1l1[8];
#pragma unroll
      for (int kc = 0; kc < 8; kc++) {
        const f16* a1b = a1p + (kc << 4);
        a1h0[kc] = *(const half8_t*)(a1b);
        a1h1[kc] = *(const half8_t*)(a1b + 32 * 128);
        a1l0[kc] = *(const half8_t*)(a1b + NW1);
        a1l1[kc] = *(const half8_t*)(a1b + NW1 + 32 * 128);
      }
      half8_t a2h0[8], a2h1[8], a2l0[8], a2l1[8];
#pragma unroll
      for (int kc = 0; kc < 8; kc++) {
        const f16* a2b = a2p + (kc << 4);
        a2h0[kc] = *(const half8_t*)(a2b);
        a2h1[kc] = *(const half8_t*)(a2b + 32 * 256);
        a2l0[kc] = *(const half8_t*)(a2b + NW1);
        a2l1[kc] = *(const half8_t*)(a2b + NW1 + 32 * 256);
      }

      // ---- GEMM1: 2 A-tile chains, 2 shared LDS reads per kc ----
      f32x16 acc1[2];
#pragma unroll
      for (int i = 0; i < 16; i++) { acc1[0][i] = 0.f; acc1[1][i] = 0.f; }
#pragma unroll
      for (int kc = 0; kc < 8; kc++) {
        int poff = (((kc << 4) + (koct << 3)) + rot0) & 127;
        half8_t bh = *(const half8_t*)(Zr + poff);
        half8_t bl = *(const half8_t*)(Zr + HLO + poff);
        acc1[0] = mfma_f16(a1h0[kc], bh, acc1[0]);
        acc1[1] = mfma_f16(a1h1[kc], bh, acc1[1]);
        acc1[0] = mfma_f16(a1l0[kc], bh, acc1[0]);
        acc1[1] = mfma_f16(a1l1[kc], bh, acc1[1]);
        acc1[0] = mfma_f16(a1h0[kc], bl, acc1[0]);
        acc1[1] = mfma_f16(a1h1[kc], bl, acc1[1]);
      }
      // epilogue1: relu, rescale (x 2^-8), split, store H[mrow][h_local]
#pragma unroll
      for (int ht = 0; ht < 2; ht++) {
#pragma unroll
        for (int qd = 0; qd < 4; qd++) {
          half4_t hv, lv;
#pragma unroll
          for (int j = 0; j < 4; j++) {
            float tv = fmaxf(acc1[ht][(qd << 2) + j], 0.f) * 0.00390625f;
            f16 h = (f16)tv; hv[j] = h; lv[j] = (f16)(tv - (float)h);
          }
          int c = (((hg << 6) + (ht << 5) + (qd << 3) + (koct << 2)) + rot0) & 127;
          *(half4_t*)(Hh + (mrow << 7) + c) = hv;
          *(half4_t*)(Hh + HLO + (mrow << 7) + c) = lv;
        }
      }
      __syncthreads();
      // ---- GEMM2 partial: 2 A-tile chains, 2 shared LDS reads per kc ----
#pragma unroll
      for (int kc = 0; kc < 8; kc++) {
        int poff = (((kc << 4) + (koct << 3)) + rot0) & 127;
        half8_t bh = *(const half8_t*)(Hr + poff);
        half8_t bl = *(const half8_t*)(Hr + HLO + poff);
        acc2[0] = mfma_f16(a2h0[kc], bh, acc2[0]);
        acc2[1] = mfma_f16(a2h1[kc], bh, acc2[1]);
        acc2[0] = mfma_f16(a2l0[kc], bh, acc2[0]);
        acc2[1] = mfma_f16(a2l1[kc], bh, acc2[1]);
        acc2[0] = mfma_f16(a2h0[kc], bl, acc2[0]);
        acc2[1] = mfma_f16(a2h1[kc], bl, acc2[1]);
      }
      __syncthreads();
    }
    // ---- epilogue2: Z[mrow][d-tiles {2hg,2hg+1}] += acc2 * 2^-8 (scaled) ----
#pragma unroll
    for (int dt = 0; dt < 2; dt++) {
      f16* zhr = Zh + (mrow << 7);
#pragma unroll
      for (int qd = 0; qd < 4; qd++) {
        int c = (((hg << 6) + (dt << 5) + (qd << 3) + (koct << 2)) + rot0) & 127;
        half4_t zh = *(half4_t*)(zhr + c);
        half4_t zl = *(half4_t*)(zhr + HLO + c);
#pragma unroll
        for (int j = 0; j < 4; j++) {
          float zs = (float)zh[j] + (float)zl[j];
          zs += acc2[dt][(qd << 2) + j] * 0.00390625f;
          f16 h = (f16)zs; zh[j] = h; zl[j] = (f16)(zs - (float)h);
        }
        *(half4_t*)(zhr + c) = zh;
        *(half4_t*)(zhr + HLO + c) = zl;
      }
    }
    __syncthreads();
  }

  // ---- dist = ||rb - z||^2 over 64 rows (4 threads/row, 32 d each) ----
  float* pd = (float*)Hh;
  int* rwin = (int*)Hh + 64;
  {
    int row = tx >> 2, seg = tx & 3;
    int rotr = (row & 15) << 3;
    const f16* zhr = Zh + (row << 7);
    const float* rb = ws + WS_RB + b * 128 + (seg << 5);
    float s = 0.f;
#pragma unroll
    for (int o = 0; o < 4; o++) {
      int c = (((seg << 5) + (o << 3)) + rotr) & 127;
      half8_t zh = *(const half8_t*)(zhr + c);
      half8_t zl = *(const half8_t*)(zhr + HLO + c);
      float4 r0 = *(const float4*)(rb + (o << 3));
      float4 r1 = *(const float4*)(rb + (o << 3) + 4);
      float rr[8] = {r0.x, r0.y, r0.z, r0.w, r1.x, r1.y, r1.z, r1.w};
#pragma unroll
      for (int j = 0; j < 8; j++) {
        float z = ((float)zh[j] + (float)zl[j]) * 0.00390625f;
        float dlt = rr[j] - z;
        s += dlt * dlt;
      }
    }
    s += __shfl_xor(s, 1);   // all 4 lanes of a row end bit-identical
    s += __shfl_xor(s, 2);
    if (seg == 0) pd[row] = s;
  }
  __syncthreads();
  if (tx < 64) {
    float v = pd[tx]; int idx = tx;
#pragma unroll
    for (int off = 32; off; off >>= 1) {
      float v2 = __shfl_xor(v, off);
      int   i2 = __shfl_xor(idx, off);
      if (v2 < v || (v2 == v && i2 < idx)) { v = v2; idx = i2; }
    }
    if (tx == 0) {
      ws[WS_BESTD + (b << 2) + t] = v;
      ((int*)ws)[WS_BESTI + (b << 2) + t] = k0 + idx;
      rwin[0] = idx;
    }
  }
  __syncthreads();
  if (tx < 32) {
    int rw = rwin[0];
    int c = ((tx << 2) + ((rw & 15) << 3)) & 127;
    half4_t zh = *(const half4_t*)(Zh + (rw << 7) + c);
    half4_t zl = *(const half4_t*)(Zh + HLO + (rw << 7) + c);
    float4 z;
    z.x = ((float)zh[0] + (float)zl[0]) * 0.00390625f;
    z.y = ((float)zh[1] + (float)zl[1]) * 0.00390625f;
    z.z = ((float)zh[2] + (float)zl[2]) * 0.00390625f;
    z.w = ((float)zh[3] + (float)zl[3]) * 0.00390625f;
    *(float4*)(ws + WS_BESTZ + (((b << 2) + t) << 7) + (tx << 2)) = z;
  }
}

// ---------------- per-step update: pick tile winner, advance xhat ----------------
__global__ __launch_bounds__(128) void k_update(const float* __restrict__ x,
    float* __restrict__ ws, float* __restrict__ out, int m, int last)
{
  __shared__ int tsel;
  int tx = threadIdx.x, b = blockIdx.x;
  if (tx == 0) {
    float bv = ws[WS_BESTD + (b << 2)]; int bt = 0;
    for (int q = 1; q < 4; q++) {
      float v = ws[WS_BESTD + (b << 2) + q];
      if (v < bv) { bv = v; bt = q; }     // strict <: ties -> lowest k (tile order)
    }
    tsel = bt;
    int k = ((const int*)ws)[WS_BESTI + (b << 2) + bt];
    out[OUT_CODES + b * 8 + (m + 1)] = (float)k;
  }
  __syncthreads();
  int bt = tsel;
  float z  = ws[WS_BESTZ + (((b << 2) + bt) << 7) + tx];
  float xh = ws[WS_XHAT + b * 128 + tx] + z;
  ws[WS_XHAT + b * 128 + tx] = xh;
  ws[WS_RB   + b * 128 + tx] = x[b * 128 + tx] - xh;
  out[OUT_SIDE + (m + 1) * 131072 + b * 128 + tx] = xh;
  if (last) out[b * 128 + tx] = xh;       // final xhat == side[7]
}

extern "C" void kernel_launch(void* const* d_in, const int* in_sizes, int n_in,
                              void* d_out, int out_size, void* d_ws, size_t ws_size,
                              hipStream_t stream)
{
  const float* x   = (const float*)d_in[0];
  const float* cb0 = (const float*)d_in[1];
  const float* cbs = (const float*)d_in[2];
  const float* Wc  = (const float*)d_in[3];
  const float* bc  = (const float*)d_in[4];
  const float* W1  = (const float*)d_in[5];
  const float* W2  = (const float*)d_in[6];
  float* out = (float*)d_out;
  float* ws  = (float*)d_ws;
  f16* wsh = (f16*)(ws + WS_WSPLIT);

  k_wsplit<<<896, 256, 0, stream>>>(W1, W2, wsh);
  k_step0<<<1024, 256, 0, stream>>>(x, cb0, ws, out);
  for (int m = 0; m < 7; m++) {
    k_prep<<<1280, 128, 0, stream>>>(cbs + m * 256 * 128, Wc + m * 128 * 256,
                                     bc + m * 128, ws);
    k_step<<<4096, 256, 0, stream>>>(wsh, ws, m);
    k_update<<<1024, 128, 0, stream>>>(x, ws, out, m, (m == 6) ? 1 : 0);
  }
}